// Round 11
// baseline (420.311 us; speedup 1.0000x reference)
//
#include <hip/hip_runtime.h>
#include <stdint.h>

// HamiltonianFlow: x [256, 8, 32, 2] (q,p); H = 0.5*sum(p^2) + MLP(q).
// dq/dt = p, dp/dt = -W1 @ [(1-tanh(z)^2) * W2], z = q^T W1 + b1.
// 100 RK4 steps = 400 strictly sequential fwd+bwd 256x256 matvecs.
//
// R11 = R10 dataflow at R8 occupancy. Evidence: R10 (4 waves/SIMD) MFMA
// pipe hits its 1033 cyc/eval floor when busy (MfmaUtil 50%), wall 2312 —
// gap is VALU (925 cyc, suspect AGPR weight placement: VGPR_Count=56 < 64
// weight regs) + serial latency. R8 (2 waves/SIMD, 2 tiles/wave) = 2610 cyc
// carrying ~550 cyc bank conflicts + extract tree + g bounce; cleaned it
// projects BELOW R10. So: 512 threads (8 waves, 2/SIMD, 256-reg budget so
// the 128 weight VGPRs can stay architectural), wave w owns tiles {2w,2w+1},
// both directions column-owned (result = C[0], no extract tree, no bounce):
//   fwd: A = q-replicated (uniform b128 bcast), B = W^T frag
//        B[k=8q+j][n=s] = W[32kk+8q+j][comp]  -> D[.][s] = z[comp]
//   bwd: A = u-replicated, B = W-row frag (contiguous b128)
//        B[k=8q+j][n=s] = W[comp][32kk+8q+j]  -> D[.][s] = g[comp]
// comp in {32w+s, 32w+16+s}; quads duplicate (exec-masked LDS writes).
// 2 barriers/eval (structurally minimal: z needs all q, g needs all u).
// FULL unroll on all reg arrays (R4: dynamic index => scratch spill).
// Numerics: f16 storage, fp32 MFMA accumulate (R3/5/7/8/10 class, 1.95e-3).

typedef _Float16 v8h __attribute__((ext_vector_type(8)));
typedef _Float16 v4h __attribute__((ext_vector_type(4)));
typedef float v4f __attribute__((ext_vector_type(4)));

#define NSTEPS 100
#define WS 264   // padded f16 row stride (528 B: rows 16B-aligned, bank shift)

__global__ __launch_bounds__(512, 2)
void ham_kernel(const float* __restrict__ x0, const float* __restrict__ W1,
                const float* __restrict__ b1, const float* __restrict__ W2,
                float* __restrict__ out)
{
    __shared__ __align__(16) _Float16 wlds[256 * WS];   // 135168 B staged W1
    __shared__ __align__(16) _Float16 qsh[256];
    __shared__ __align__(16) _Float16 ush[256];

    const int t = threadIdx.x;
    const int w = t >> 6;          // wave 0..7: owns tiles {2w,2w+1}
    const int l = t & 63;
    const int quad = l >> 4;       // K-subgroup
    const int s = l & 15;          // owned column
    const int c0 = 32 * w + s;     // owned comp, tile 2w
    const int c1 = c0 + 16;        // owned comp, tile 2w+1
    const int blk = blockIdx.x;

    // ---- stage W1 -> LDS f16 (padded rows), coalesced ----
    #pragma unroll 1
    for (int k = t; k < 65536 / 4; k += 512) {
        const int row = k >> 6, col4 = (k & 63) * 4;
        float4 v = ((const float4*)W1)[k];
        v4h h; h[0] = (_Float16)v.x; h[1] = (_Float16)v.y;
               h[2] = (_Float16)v.z; h[3] = (_Float16)v.w;
        *(v4h*)(wlds + row * WS + col4) = h;
    }
    __syncthreads();

    // ---- weight B-frags, both orientations, both tiles, FULL unroll ----
    // wF0/wF1 (fwd):  elem j = W[32kk+8quad+j][c0 / c1]   (column gather)
    // wB0/wB1 (bwd):  elem j = W[c0 / c1][32kk+8quad+j]   (contiguous b128)
    v8h wF0[8], wF1[8], wB0[8], wB1[8];
    #pragma unroll
    for (int kk = 0; kk < 8; ++kk) {
        wB0[kk] = *(const v8h*)(wlds + c0 * WS + 32 * kk + 8 * quad);
        wB1[kk] = *(const v8h*)(wlds + c1 * WS + 32 * kk + 8 * quad);
        #pragma unroll
        for (int j = 0; j < 8; ++j) {
            wF0[kk][j] = wlds[(32 * kk + 8 * quad + j) * WS + c0];
            wF1[kk][j] = wlds[(32 * kk + 8 * quad + j) * WS + c1];
        }
    }

    const float b1r0 = b1[c0], b1r1 = b1[c1];
    const float w2r0 = W2[c0], w2r1 = W2[c1];

    float2 qp0 = ((const float2*)(x0 + (size_t)blk * 512))[c0];
    float2 qp1 = ((const float2*)(x0 + (size_t)blk * 512))[c1];
    float q00 = qp0.x, p00 = qp0.y;
    float q01 = qp1.x, p01 = qp1.y;
    if (quad == 0) { qsh[c0] = (_Float16)q00; qsh[c1] = (_Float16)q01; }
    __syncthreads();

    const float dt = 0.01f;
    float accq0 = 0.f, accp0 = 0.f, qs0 = q00, ps0 = p00;
    float accq1 = 0.f, accp1 = 0.f, qs1 = q01, ps1 = p01;

    // hoisted LDS bases for the broadcast operand reads
    const _Float16* qb = qsh + 8 * quad;
    const _Float16* ub = ush + 8 * quad;

    #pragma unroll 1
    for (int it = 0; it < NSTEPS * 4; ++it) {
        const int stg = it & 3;

        // ---- forward: z[c0], z[c1] via A=q-replicated, B=wF* ----
        v4f C0a = {0,0,0,0}, C0b = {0,0,0,0}, C1a = {0,0,0,0}, C1b = {0,0,0,0};
        #pragma unroll
        for (int kk = 0; kk < 8; kk += 2) {
            v8h a0 = *(const v8h*)(qb + 32 * kk);         // bcast b128
            v8h a1 = *(const v8h*)(qb + 32 * (kk + 1));   // bcast b128
            C0a = __builtin_amdgcn_mfma_f32_16x16x32_f16(a0, wF0[kk], C0a, 0, 0, 0);
            C1a = __builtin_amdgcn_mfma_f32_16x16x32_f16(a0, wF1[kk], C1a, 0, 0, 0);
            C0b = __builtin_amdgcn_mfma_f32_16x16x32_f16(a1, wF0[kk + 1], C0b, 0, 0, 0);
            C1b = __builtin_amdgcn_mfma_f32_16x16x32_f16(a1, wF1[kk + 1], C1b, 0, 0, 0);
        }
        float z0 = C0a[0] + C0b[0] + b1r0;
        float z1 = C1a[0] + C1b[0] + b1r1;

        // ---- nonlinearity, both owned comps (ILP pair) ----
        float e0 = __expf(2.f * z0), e1 = __expf(2.f * z1);
        float h0 = 1.f - 2.f / (e0 + 1.f), h1 = 1.f - 2.f / (e1 + 1.f);
        float u0 = (1.f - h0 * h0) * w2r0, u1 = (1.f - h1 * h1) * w2r1;
        if (quad == 0) { ush[c0] = (_Float16)u0; ush[c1] = (_Float16)u1; }
        __syncthreads();

        // ---- backward: g[c0], g[c1] via A=u-replicated, B=wB* ----
        v4f G0a = {0,0,0,0}, G0b = {0,0,0,0}, G1a = {0,0,0,0}, G1b = {0,0,0,0};
        #pragma unroll
        for (int kk = 0; kk < 8; kk += 2) {
            v8h a0 = *(const v8h*)(ub + 32 * kk);         // bcast b128
            v8h a1 = *(const v8h*)(ub + 32 * (kk + 1));   // bcast b128
            G0a = __builtin_amdgcn_mfma_f32_16x16x32_f16(a0, wB0[kk], G0a, 0, 0, 0);
            G1a = __builtin_amdgcn_mfma_f32_16x16x32_f16(a0, wB1[kk], G1a, 0, 0, 0);
            G0b = __builtin_amdgcn_mfma_f32_16x16x32_f16(a1, wB0[kk + 1], G0b, 0, 0, 0);
            G1b = __builtin_amdgcn_mfma_f32_16x16x32_f16(a1, wB1[kk + 1], G1b, 0, 0, 0);
        }
        float g0 = G0a[0] + G0b[0];
        float g1 = G1a[0] + G1b[0];

        // ---- RK4 bookkeeping, both owned comps ----
        float wgt = (stg == 0 || stg == 3) ? 1.f : 2.f;
        float kq0 = ps0, kp0 = -g0, kq1 = ps1, kp1 = -g1;
        accq0 += wgt * kq0; accp0 += wgt * kp0;
        accq1 += wgt * kq1; accp1 += wgt * kp1;
        float qn0, qn1;
        if (stg < 3) {
            float a = (stg == 2) ? dt : 0.5f * dt;
            qs0 = q00 + a * kq0;  ps0 = p00 + a * kp0;
            qs1 = q01 + a * kq1;  ps1 = p01 + a * kp1;
            qn0 = qs0; qn1 = qs1;
        } else {
            q00 += (dt / 6.f) * accq0;  p00 += (dt / 6.f) * accp0;
            q01 += (dt / 6.f) * accq1;  p01 += (dt / 6.f) * accp1;
            accq0 = 0.f; accp0 = 0.f; accq1 = 0.f; accp1 = 0.f;
            qs0 = q00; ps0 = p00; qs1 = q01; ps1 = p01;
            qn0 = q00; qn1 = q01;
        }
        if (quad == 0) { qsh[c0] = (_Float16)qn0; qsh[c1] = (_Float16)qn1; }
        __syncthreads();
    }

    if (quad == 0) {
        ((float2*)(out + (size_t)blk * 512))[c0] = make_float2(q00, p00);
        ((float2*)(out + (size_t)blk * 512))[c1] = make_float2(q01, p01);
    }
}

extern "C" void kernel_launch(void* const* d_in, const int* in_sizes, int n_in,
                              void* d_out, int out_size, void* d_ws, size_t ws_size,
                              hipStream_t stream) {
    const float* x0 = (const float*)d_in[0];
    const float* W1 = (const float*)d_in[1];
    const float* b1 = (const float*)d_in[2];
    const float* W2 = (const float*)d_in[3];
    // d_in[4] = b2: constant offset, no effect on the gradient/dynamics.
    float* out = (float*)d_out;
    hipLaunchKernelGGL(ham_kernel, dim3(256), dim3(512), 0, stream,
                       x0, W1, b1, W2, out);
}

// Round 12
// 401.931 us; speedup vs baseline: 1.0457x; 1.0457x over previous
//
#include <hip/hip_runtime.h>
#include <stdint.h>

// HamiltonianFlow: x [256, 8, 32, 2] (q,p); H = 0.5*sum(p^2) + MLP(q).
// dq/dt = p, dp/dt = -W1 @ [(1-tanh(z)^2) * W2], z = q^T W1 + b1.
// 100 RK4 steps = 400 sequential stages.
//
// R12: SINGLE-PHASE PIPELINE. RK4 dependency analysis: kq_s = p0 - a_s*g_{s-1}
// -> the NEXT stage's q is computable before the current backward matvec.
// So fwd(s+1) and bwd(s) are independent => merged into ONE MFMA block:
//   iter top (VALU): u_s = act(z_s); RK4 update from g_{s-1}; q_{s+1}
//   write u_s, q_{s+1} (double-buffered) ; ONE barrier
//   MFMA x16: g_s = W u_s  AND  z_{s+1} = W^T q_{s+1}   (4 indep chains)
// Halves barriers and serial tails vs R10 (which was: MFMA pipe at its
// 1033 cyc/eval floor when busy, wall 2312 => tails dominate).
// Double-buffer correctness: iter i writes buf i&1 before its barrier and
// reads it after; iter i+2's writes to the same buf are fenced by barrier
// i+1 (slow wave arrives there only after its iter-i reads completed).
//
// Layout (R10-verified, passed 1.95e-3): mfma_f32_16x16x32_f16,
//   fwd: A = q-replicated (uniform b128 bcast), B-frag wF[kk][j] =
//        W[32kk+8quad+j][comp]  -> D[.][s] = z[comp]
//   bwd: A = u-replicated, B-frag wBt[kk][j] = W[comp][32kk+8quad+j]
//        (contiguous b128)      -> D[.][s] = g[comp]
// comp = 16w+s, quads duplicate. b1 folded into fwd C-init (rows equal).
// 1024 threads (16 waves, 4/SIMD). FULL unroll on all reg arrays (R4).
// Numerics: f16 storage, fp32 MFMA accumulate (R3/5/7/8/10 class).

typedef _Float16 v8h __attribute__((ext_vector_type(8)));
typedef _Float16 v4h __attribute__((ext_vector_type(4)));
typedef float v4f __attribute__((ext_vector_type(4)));

#define NSTEPS 100
#define WS 264   // padded f16 row stride (528 B: rows 16B-aligned, bank shift)

__global__ __launch_bounds__(1024, 4)
void ham_kernel(const float* __restrict__ x0, const float* __restrict__ W1,
                const float* __restrict__ b1, const float* __restrict__ W2,
                float* __restrict__ out)
{
    __shared__ __align__(16) _Float16 wlds[256 * WS];   // 135168 B staged W1
    __shared__ __align__(16) _Float16 qsh[2][256];      // double-buffered
    __shared__ __align__(16) _Float16 ush[2][256];

    const int t = threadIdx.x;
    const int w = t >> 6;          // wave 0..15: owns tile w
    const int l = t & 63;
    const int quad = l >> 4;       // K-subgroup
    const int s = l & 15;          // owned column
    const int comp = 16 * w + s;   // owned component (dup across quads)
    const int blk = blockIdx.x;

    // ---- stage W1 -> LDS f16 (padded rows), coalesced ----
    #pragma unroll 1
    for (int k = t; k < 65536 / 4; k += 1024) {
        const int row = k >> 6, col4 = (k & 63) * 4;
        float4 v = ((const float4*)W1)[k];
        v4h h; h[0] = (_Float16)v.x; h[1] = (_Float16)v.y;
               h[2] = (_Float16)v.z; h[3] = (_Float16)v.w;
        *(v4h*)(wlds + row * WS + col4) = h;
    }
    __syncthreads();

    // ---- weight B-frags, both orientations, FULL unroll ----
    v8h wF[8], wBt[8];
    #pragma unroll
    for (int kk = 0; kk < 8; ++kk) {
        wBt[kk] = *(const v8h*)(wlds + comp * WS + 32 * kk + 8 * quad);
        #pragma unroll
        for (int j = 0; j < 8; ++j)
            wF[kk][j] = wlds[(32 * kk + 8 * quad + j) * WS + comp];
    }

    const float b1r = b1[comp];
    const float w2r = W2[comp];

    float2 qp = ((const float2*)(x0 + (size_t)blk * 512))[comp];
    float q0 = qp.x, p0 = qp.y;

    const float dt = 0.01f, hdt = 0.005f, dt6 = 0.01f / 6.f;

    // ---- prologue: z_1 = W^T q0 + b1 (buffer 1) ----
    if (quad == 0) qsh[1][comp] = (_Float16)q0;
    __syncthreads();
    float z, g = 0.f, accq = 0.f, accp = 0.f;
    {
        v4f Ca = {b1r, b1r, b1r, b1r}, Cb = {0, 0, 0, 0};
        const _Float16* qb = &qsh[1][0] + 8 * quad;
        #pragma unroll
        for (int kk = 0; kk < 8; kk += 2) {
            v8h a0 = *(const v8h*)(qb + 32 * kk);
            v8h a1 = *(const v8h*)(qb + 32 * (kk + 1));
            Ca = __builtin_amdgcn_mfma_f32_16x16x32_f16(a0, wF[kk], Ca, 0, 0, 0);
            Cb = __builtin_amdgcn_mfma_f32_16x16x32_f16(a1, wF[kk + 1], Cb, 0, 0, 0);
        }
        z = Ca[0] + Cb[0];
    }

    #pragma unroll 1
    for (int it = 0; it < NSTEPS * 4; ++it) {
        const int stg = it & 3;
        const int buf = it & 1;

        // ---- u_s from z_s ----
        float e = __expf(2.f * z);            // tanh via exp; saturates ok
        float hh = 1.f - 2.f / (e + 1.f);
        float u = (1.f - hh * hh) * w2r;

        // ---- RK4 bookkeeping with g_{s-1}; compute q_{s+1} ----
        float kq, qnext;
        if (stg == 0) {
            if (it) { accp -= g; p0 += dt6 * accp; }  // finish prev step's p
            kq = p0; accq = kq;
            qnext = q0 + hdt * kq;
        } else if (stg == 1) {
            accp = -g;                  // kp1, wgt 1
            kq = p0 - hdt * g;          // kq2
            accq += 2.f * kq;
            qnext = q0 + hdt * kq;
        } else if (stg == 2) {
            accp -= 2.f * g;            // kp2, wgt 2
            kq = p0 - hdt * g;          // kq3
            accq += 2.f * kq;
            qnext = q0 + dt * kq;
        } else {
            accp -= 2.f * g;            // kp3, wgt 2
            kq = p0 - dt * g;           // kq4
            accq += kq;
            q0 += dt6 * accq;           // finish q for this step
            qnext = q0;
        }

        if (quad == 0) {
            ush[buf][comp] = (_Float16)u;
            qsh[buf][comp] = (_Float16)qnext;
        }
        __syncthreads();

        // ---- merged MFMA: g_s = W u_s ; z_{s+1} = W^T q_{s+1} + b1 ----
        const _Float16* ub = &ush[buf][0] + 8 * quad;
        const _Float16* qb = &qsh[buf][0] + 8 * quad;
        v4f Ga = {0, 0, 0, 0}, Gb = {0, 0, 0, 0};
        v4f Ca = {b1r, b1r, b1r, b1r}, Cb = {0, 0, 0, 0};
        #pragma unroll
        for (int kk = 0; kk < 8; kk += 2) {
            v8h au0 = *(const v8h*)(ub + 32 * kk);
            v8h aq0 = *(const v8h*)(qb + 32 * kk);
            v8h au1 = *(const v8h*)(ub + 32 * (kk + 1));
            v8h aq1 = *(const v8h*)(qb + 32 * (kk + 1));
            Ga = __builtin_amdgcn_mfma_f32_16x16x32_f16(au0, wBt[kk], Ga, 0, 0, 0);
            Ca = __builtin_amdgcn_mfma_f32_16x16x32_f16(aq0, wF[kk], Ca, 0, 0, 0);
            Gb = __builtin_amdgcn_mfma_f32_16x16x32_f16(au1, wBt[kk + 1], Gb, 0, 0, 0);
            Cb = __builtin_amdgcn_mfma_f32_16x16x32_f16(aq1, wF[kk + 1], Cb, 0, 0, 0);
        }
        g = Ga[0] + Gb[0];
        z = Ca[0] + Cb[0];
    }

    // ---- epilogue: finish p with g_4 of the last step ----
    accp -= g;
    p0 += dt6 * accp;

    if (quad == 0)
        ((float2*)(out + (size_t)blk * 512))[comp] = make_float2(q0, p0);
}

extern "C" void kernel_launch(void* const* d_in, const int* in_sizes, int n_in,
                              void* d_out, int out_size, void* d_ws, size_t ws_size,
                              hipStream_t stream) {
    const float* x0 = (const float*)d_in[0];
    const float* W1 = (const float*)d_in[1];
    const float* b1 = (const float*)d_in[2];
    const float* W2 = (const float*)d_in[3];
    // d_in[4] = b2: constant offset, no effect on the gradient/dynamics.
    float* out = (float*)d_out;
    hipLaunchKernelGGL(ham_kernel, dim3(256), dim3(1024), 0, stream,
                       x0, W1, b1, W2, out);
}

// Round 13
// 378.396 us; speedup vs baseline: 1.1108x; 1.0622x over previous
//
#include <hip/hip_runtime.h>
#include <stdint.h>

// HamiltonianFlow: x [256, 8, 32, 2] (q,p); H = 0.5*sum(p^2) + MLP(q).
// dq/dt = p, dp/dt = -W1 @ [(1-tanh(z)^2) * W2], z = q^T W1 + b1.
// 100 RK4 steps = 400 sequential stages (fwd+bwd matvec each).
//
// R13 = R12 single-phase pipeline + AGPR-NATIVE MFMA OPERANDS.
// Diagnosis chain: at 16 waves/CU the unified reg budget is 128/thread.
// R12: VGPR_Count=60 arch + ~64 AGPR (weights) = 124 -- weights are in
// AGPRs, and VALUBusy 40% ~= the v_accvgpr_read copy stream LLVM emits
// because the MFMA *builtin* wants A/B in VGPRs. ISA 10 says A/B may be
// AGPR directly -> inline asm with "a" constraint on the weight operand:
//   v_mfma_f32_16x16x32_f16 vD, vA, aB, vD   (weights resident in AGPR,
// zero per-use copies; accumulator in VGPR so z/g extraction is free; the
// "a" tie also pins residency, killing any LDS-rematerialization).
//
// Structure (R12, passed 1.95e-3): one block/trajectory, 1024 thr (16 waves,
// 4/SIMD). Wave w owns tile w (comps [16w,16w+16)); lane: quad=l>>4 (K-sub),
// s=l&15, comp=16w+s (quads duplicate). Per stage: VALU top (u=act(z), RK4
// with g_{s-1}, q_{s+1}), exec-masked b16 writes, ONE barrier, then merged
// MFMA block: g_s = W u_s and z_{s+1} = W^T q_{s+1} + b1 (b1 in C-init).
//   fwd B-frag wF[kk][j]  = W[32kk+8quad+j][comp]  (column gather, once)
//   bwd B-frag wBt[kk][j] = W[comp][32kk+8quad+j]  (contiguous b128, once)
// A = vector replicated over rows via wave-uniform b128 bcast reads.
// Double-buffer qsh/ush(buf=it&1): iter i+2's writes fenced by barrier i+1.
// FULL unroll on all reg arrays (R4: dynamic index => scratch spill).
// Numerics: f16 storage, fp32 MFMA accumulate (R3/5/7/8/10/12 class).

typedef _Float16 v8h __attribute__((ext_vector_type(8)));
typedef _Float16 v4h __attribute__((ext_vector_type(4)));
typedef float v4f __attribute__((ext_vector_type(4)));

#define NSTEPS 100
#define WS 264   // padded f16 row stride (528 B: rows 16B-aligned, bank shift)

// D(+=C) in VGPRs, A in VGPRs, B (weight) read directly from AGPRs.
#define MFMA_AV(C, A, B) \
    asm("v_mfma_f32_16x16x32_f16 %0, %1, %2, %0" \
        : "+v"(C) : "v"(A), "a"(B))

__global__ __launch_bounds__(1024, 4)
void ham_kernel(const float* __restrict__ x0, const float* __restrict__ W1,
                const float* __restrict__ b1, const float* __restrict__ W2,
                float* __restrict__ out)
{
    __shared__ __align__(16) _Float16 wlds[256 * WS];   // 135168 B staged W1
    __shared__ __align__(16) _Float16 qsh[2][256];      // double-buffered
    __shared__ __align__(16) _Float16 ush[2][256];

    const int t = threadIdx.x;
    const int w = t >> 6;          // wave 0..15: owns tile w
    const int l = t & 63;
    const int quad = l >> 4;       // K-subgroup
    const int s = l & 15;          // owned column
    const int comp = 16 * w + s;   // owned component (dup across quads)
    const int blk = blockIdx.x;

    // ---- stage W1 -> LDS f16 (padded rows), coalesced ----
    #pragma unroll 1
    for (int k = t; k < 65536 / 4; k += 1024) {
        const int row = k >> 6, col4 = (k & 63) * 4;
        float4 v = ((const float4*)W1)[k];
        v4h h; h[0] = (_Float16)v.x; h[1] = (_Float16)v.y;
               h[2] = (_Float16)v.z; h[3] = (_Float16)v.w;
        *(v4h*)(wlds + row * WS + col4) = h;
    }
    __syncthreads();

    // ---- weight B-frags, both orientations, FULL unroll ----
    v8h wF[8], wBt[8];
    #pragma unroll
    for (int kk = 0; kk < 8; ++kk) {
        wBt[kk] = *(const v8h*)(wlds + comp * WS + 32 * kk + 8 * quad);
        #pragma unroll
        for (int j = 0; j < 8; ++j)
            wF[kk][j] = wlds[(32 * kk + 8 * quad + j) * WS + comp];
    }

    const float b1r = b1[comp];
    const float w2r = W2[comp];

    float2 qp = ((const float2*)(x0 + (size_t)blk * 512))[comp];
    float q0 = qp.x, p0 = qp.y;

    const float dt = 0.01f, hdt = 0.005f, dt6 = 0.01f / 6.f;

    // ---- prologue: z_1 = W^T q0 + b1 (buffer 1) ----
    if (quad == 0) qsh[1][comp] = (_Float16)q0;
    __syncthreads();
    float z, g = 0.f, accq = 0.f, accp = 0.f;
    {
        v4f C = {b1r, b1r, b1r, b1r};
        const _Float16* qb = &qsh[1][0] + 8 * quad;
        #pragma unroll
        for (int kk = 0; kk < 8; ++kk) {
            v8h a = *(const v8h*)(qb + 32 * kk);
            MFMA_AV(C, a, wF[kk]);
        }
        z = C[0];
    }

    #pragma unroll 1
    for (int it = 0; it < NSTEPS * 4; ++it) {
        const int stg = it & 3;
        const int buf = it & 1;

        // ---- u_s from z_s ----
        float e = __expf(2.f * z);            // tanh via exp; saturates ok
        float hh = 1.f - 2.f / (e + 1.f);
        float u = (1.f - hh * hh) * w2r;

        // ---- RK4 bookkeeping with g_{s-1}; compute q_{s+1} ----
        float kq, qnext;
        if (stg == 0) {
            if (it) { accp -= g; p0 += dt6 * accp; }  // finish prev step's p
            kq = p0; accq = kq;
            qnext = q0 + hdt * kq;
        } else if (stg == 1) {
            accp = -g;                  // kp1, wgt 1
            kq = p0 - hdt * g;          // kq2
            accq += 2.f * kq;
            qnext = q0 + hdt * kq;
        } else if (stg == 2) {
            accp -= 2.f * g;            // kp2, wgt 2
            kq = p0 - hdt * g;          // kq3
            accq += 2.f * kq;
            qnext = q0 + dt * kq;
        } else {
            accp -= 2.f * g;            // kp3, wgt 2
            kq = p0 - dt * g;           // kq4
            accq += kq;
            q0 += dt6 * accq;           // finish q for this step
            qnext = q0;
        }

        if (quad == 0) {
            ush[buf][comp] = (_Float16)u;
            qsh[buf][comp] = (_Float16)qnext;
        }
        __syncthreads();

        // ---- merged MFMA: g_s = W u_s ; z_{s+1} = W^T q_{s+1} + b1 ----
        const _Float16* ub = &ush[buf][0] + 8 * quad;
        const _Float16* qb = &qsh[buf][0] + 8 * quad;
        v4f G = {0, 0, 0, 0};
        v4f C = {b1r, b1r, b1r, b1r};
        #pragma unroll
        for (int kk = 0; kk < 8; ++kk) {
            v8h au = *(const v8h*)(ub + 32 * kk);
            v8h aq = *(const v8h*)(qb + 32 * kk);
            MFMA_AV(G, au, wBt[kk]);
            MFMA_AV(C, aq, wF[kk]);
        }
        g = G[0];
        z = C[0];
    }

    // ---- epilogue: finish p with g_4 of the last step ----
    accp -= g;
    p0 += dt6 * accp;

    if (quad == 0)
        ((float2*)(out + (size_t)blk * 512))[comp] = make_float2(q0, p0);
}

extern "C" void kernel_launch(void* const* d_in, const int* in_sizes, int n_in,
                              void* d_out, int out_size, void* d_ws, size_t ws_size,
                              hipStream_t stream) {
    const float* x0 = (const float*)d_in[0];
    const float* W1 = (const float*)d_in[1];
    const float* b1 = (const float*)d_in[2];
    const float* W2 = (const float*)d_in[3];
    // d_in[4] = b2: constant offset, no effect on the gradient/dynamics.
    float* out = (float*)d_out;
    hipLaunchKernelGGL(ham_kernel, dim3(256), dim3(1024), 0, stream,
                       x0, W1, b1, W2, out);
}